// Round 6
// baseline (107.256 us; speedup 1.0000x reference)
//
#include <hip/hip_runtime.h>

typedef short bf16x8 __attribute__((ext_vector_type(8)));
typedef float f32x4 __attribute__((ext_vector_type(4)));
typedef float f32x16 __attribute__((ext_vector_type(16)));
typedef unsigned int u32x4 __attribute__((ext_vector_type(4)));
typedef unsigned short u16;
typedef unsigned int u32;

#define DEVI static __device__ __forceinline__

// Problem constants
#define NB 16
#define NS 2048
#define NW 768
#define NH 64

DEVI u16 f2bf(float x) {
  u32 u = __builtin_bit_cast(u32, x);
  u += 0x7fffu + ((u >> 16) & 1u);
  return (u16)(u >> 16);
}

DEVI u32 cvtpk(float lo, float hi) {
  u32 r;
  asm("v_cvt_pk_bf16_f32 %0, %1, %2" : "=v"(r) : "v"(lo), "v"(hi));
  return r;
}

DEVI bf16x8 cvt8(float4 a, float4 b) {
  u32x4 r;
  r.x = cvtpk(a.x, a.y);
  r.y = cvtpk(a.z, a.w);
  r.z = cvtpk(b.x, b.y);
  r.w = cvtpk(b.z, b.w);
  return __builtin_bit_cast(bf16x8, r);
}

DEVI f32x4 mfma16(bf16x8 a, bf16x8 b, f32x4 c) {
  return __builtin_amdgcn_mfma_f32_16x16x32_bf16(a, b, c, 0, 0, 0);
}
DEVI f32x16 mfma32(bf16x8 a, bf16x8 b, f32x16 c) {
  return __builtin_amdgcn_mfma_f32_32x32x16_bf16(a, b, c, 0, 0, 0);
}

// ---------------------------------------------------------------------------
// Fragment-linear layouts (attention loads are base + lane*16B, coalesced):
//   Q_frag/K_frag: u16[(b*64+T)][kk=0..3][lane=hi*32+l31][j=0..7]
//     holds (s, n) with T=s>>5, l31=s&31, kk=n>>4, hi=(n>>3)&1, j=n&7.
//   V_frag: u16[(b*64+T)][ks=0..1][ht=0..1][lane=hi*32+(h&31)][j]
//     holds (s, h) with ks=bit4(s&31), hi=bit3(s&31), j=s&7, ht=h>>5.
// ---------------------------------------------------------------------------

// ---------------------------------------------------------------------------
// Kernel 0: rearrange Wq/Wk/Wv (fp32 [768][64]) into bf16 MFMA-B-fragment order.
// ---------------------------------------------------------------------------
__global__ __launch_bounds__(256) void prep_weights(
    const float* __restrict__ Wq, const float* __restrict__ Wk,
    const float* __restrict__ Wv, u16* __restrict__ wsW) {
  int tid = blockIdx.x * 256 + threadIdx.x;
  int tile = tid >> 6, lane = tid & 63;
  int p = tile / 96, rem = tile % 96;
  int nct = rem / 24, kch = rem % 24;
  const float* Wsrc = (p == 0) ? Wq : ((p == 1) ? Wk : Wv);
  int k0 = kch * 32 + (lane >> 4) * 8;
  int n = nct * 16 + (lane & 15);
  u16 h[8];
#pragma unroll
  for (int i = 0; i < 8; i++) h[i] = f2bf(Wsrc[(k0 + i) * NH + n]);
  uint4 v;
  v.x = (u32)h[0] | ((u32)h[1] << 16);
  v.y = (u32)h[2] | ((u32)h[3] << 16);
  v.z = (u32)h[4] | ((u32)h[5] << 16);
  v.w = (u32)h[6] | ((u32)h[7] << 16);
  ((uint4*)wsW)[tile * 64 + lane] = v;
}

// ---------------------------------------------------------------------------
// Kernel 0b: mask -> additive float bias (0 valid, -1e5 masked).
// ---------------------------------------------------------------------------
__global__ __launch_bounds__(256) void prep_bias(const int* __restrict__ mask,
                                                 float* __restrict__ biasF) {
  int i = blockIdx.x * 256 + threadIdx.x;
  biasF[i] = mask[i] ? 0.0f : -1.0e5f;
}

// ---------------------------------------------------------------------------
// Kernel 1: fused QKV projection, NO LDS / NO barriers.
// BM=32 rows/block, 4 waves each own 48 output cols. A-fragments read
// directly from global fp32 (4 waves share the same 8KB/chunk -> L1 dedup),
// converted in-register with v_cvt_pk_bf16_f32. W fragments from frag-ordered
// workspace (L2-resident). Compiler free to pipeline across chunks.
// ---------------------------------------------------------------------------
__global__ __launch_bounds__(256) void qkv_proj(
    const float* __restrict__ inp, const u16* __restrict__ wsW,
    const float* __restrict__ bq, const float* __restrict__ bk,
    const float* __restrict__ bv, u16* __restrict__ Qf, u16* __restrict__ Kf,
    u16* __restrict__ Vf) {
  int tid = threadIdx.x;
  int w = tid >> 6, lane = tid & 63, g = lane >> 4, l15 = lane & 15;
  int row0 = blockIdx.x * 32;

  f32x4 acc[2][3];
#pragma unroll
  for (int rt = 0; rt < 2; rt++)
#pragma unroll
    for (int ct = 0; ct < 3; ct++) acc[rt][ct] = (f32x4)0.0f;

#pragma unroll 2
  for (int chunk = 0; chunk < 12; chunk++) {
    const float* cb = inp + (size_t)row0 * NW + chunk * 64;
    // A: 16 rows x 64 cols fp32, this lane's 2x float4 per (rt,kk)
    float4 a[2][2][2];
#pragma unroll
    for (int rt = 0; rt < 2; rt++)
#pragma unroll
      for (int kk = 0; kk < 2; kk++) {
        const float* p = cb + (size_t)(rt * 16 + l15) * NW + kk * 32 + g * 8;
        a[rt][kk][0] = *(const float4*)p;
        a[rt][kk][1] = *(const float4*)(p + 4);
      }
    // W fragments for this wave's 3 col-tiles
    bf16x8 wr[3][2];
#pragma unroll
    for (int ct = 0; ct < 3; ct++)
#pragma unroll
      for (int kk = 0; kk < 2; kk++)
        wr[ct][kk] = *(const bf16x8*)(
            wsW + (size_t)((w * 3 + ct) * 24 + chunk * 2 + kk) * 512 + lane * 8);
    // Convert + MFMA
    bf16x8 af[2][2];
#pragma unroll
    for (int rt = 0; rt < 2; rt++)
#pragma unroll
      for (int kk = 0; kk < 2; kk++)
        af[rt][kk] = cvt8(a[rt][kk][0], a[rt][kk][1]);
#pragma unroll
    for (int ct = 0; ct < 3; ct++)
#pragma unroll
      for (int kk = 0; kk < 2; kk++) {
        acc[0][ct] = mfma16(af[0][kk], wr[ct][kk], acc[0][ct]);
        acc[1][ct] = mfma16(af[1][kk], wr[ct][kk], acc[1][ct]);
      }
  }

  // Epilogue: bias add, store in fragment-linear order.
  int b = row0 >> 11;
  size_t bT = (size_t)b * 64 + ((row0 & 2047) >> 5);
#pragma unroll
  for (int ct = 0; ct < 3; ct++) {
    int gct = w * 3 + ct;
    int p3 = gct >> 2;
    int n = (gct & 3) * 16 + l15;
    const float* bias = (p3 == 0) ? bq : ((p3 == 1) ? bk : bv);
    float bbv = bias[n];
    if (p3 < 2) {
      u16* base = (p3 == 0) ? Qf : Kf;
      int kk = gct & 3;
      int hin = (l15 >> 3) & 1, j = l15 & 7;
#pragma unroll
      for (int rt = 0; rt < 2; rt++)
#pragma unroll
        for (int reg = 0; reg < 4; reg++)
          base[((bT * 4 + kk) * 64 + hin * 32 + rt * 16 + g * 4 + reg) * 8 + j] =
              f2bf(acc[rt][ct][reg] + bbv);
    } else {
      int ht = n >> 5, lanev = ((g >> 1) & 1) * 32 + (n & 31), jb = (g & 1) * 4;
#pragma unroll
      for (int rt = 0; rt < 2; rt++) {
        uint2 pp;
        pp.x = (u32)f2bf(acc[rt][ct][0] + bbv) |
               ((u32)f2bf(acc[rt][ct][1] + bbv) << 16);
        pp.y = (u32)f2bf(acc[rt][ct][2] + bbv) |
               ((u32)f2bf(acc[rt][ct][3] + bbv) << 16);
        *(uint2*)(Vf + (((bT * 2 + rt) * 2 + ht) * 64 + lanev) * 8 + jb) = pp;
      }
    }
  }
}

// ---------------------------------------------------------------------------
// Kernel 2: flash attention, 32x32 MFMA, fragment-linear operands.
// Block: 64 q-rows x batch, 8 waves = 2 q-tiles x 4 KV-chunks. The two
// q-tile waves of a chunk read identical K/V lines -> L1 dedup (halves L2
// traffic). All operand loads base + lane*16B. Swapped QK^T; additive mask
// bias; defer-max; P packed via cvt_pk + v_permlane32_swap (no shfl/select).
// ---------------------------------------------------------------------------
__global__ __launch_bounds__(512) void attn(
    const u16* __restrict__ Qf, const u16* __restrict__ Kf,
    const u16* __restrict__ Vf, const float* __restrict__ biasF,
    float* __restrict__ out) {
  // Main loop: corrL (8 waves x 32 f32, wave-private). After the final
  // barrier aliased as accL[4][64][65] f32 + mlL[4][64][2] f32.
  __shared__ __align__(16) char smem[68608];
  int tid = threadIdx.x;
  int w = tid >> 6, lane = tid & 63;
  int l31 = lane & 31, hi = lane >> 5;
  int qt = w >> 2, kc = w & 3;
  int bid = blockIdx.x;
  int b = (bid & 7) * 2 + ((bid >> 3) & 1);  // 2 batches per XCD (L2 locality)
  int qp = bid >> 4;                         // 64-q pair index 0..31
  const float* bb = biasF + (size_t)b * NS;
  float* corrL = (float*)smem + w * 32;

  const float SC = 0.18033688011112043f;  // log2(e)/sqrt(64)

  // Q fragments for this wave's q-tile
  size_t bQT = (size_t)b * 64 + qp * 2 + qt;
  bf16x8 qf[4];
#pragma unroll
  for (int kk = 0; kk < 4; kk++)
    qf[kk] = *(const bf16x8*)(Qf + (bQT * 4 + kk) * 512 + lane * 8);

  f32x16 acc[2];
  acc[0] = (f32x16)0.0f;
  acc[1] = (f32x16)0.0f;
  float m_run = -1.0e4f, l_run = 0.0f;

  // First K tile of this wave's 512-key chunk
  size_t tbase = (size_t)b * 64 + kc * 16;
  bf16x8 kf[4];
#pragma unroll
  for (int kk = 0; kk < 4; kk++)
    kf[kk] = *(const bf16x8*)(Kf + (tbase * 4 + kk) * 512 + lane * 8);

  for (int t = 0; t < 16; t++) {
    int kv0 = kc * 512 + t * 32;
    size_t bKT = tbase + t;
    size_t bKN = tbase + ((t < 15) ? t + 1 : t);
    // Prefetch next K tile (register double-buffer)
    bf16x8 kn[4];
#pragma unroll
    for (int kk = 0; kk < 4; kk++)
      kn[kk] = *(const bf16x8*)(Kf + (bKN * 4 + kk) * 512 + lane * 8);
    // V fragments + bias: issued now, consumed after softmax (self-hiding)
    bf16x8 vf[2][2];
#pragma unroll
    for (int ht = 0; ht < 2; ht++)
#pragma unroll
      for (int ks = 0; ks < 2; ks++)
        vf[ht][ks] = *(const bf16x8*)(Vf + ((bKT * 2 + ks) * 2 + ht) * 512 +
                                      lane * 8);
    float4 b4[4];
#pragma unroll
    for (int m = 0; m < 4; m++)
      b4[m] = *(const float4*)(bb + kv0 + m * 8 + hi * 4);

    // S^T[key][q] : lane holds q=l31, keys (r&3)+8*(r>>2)+4*hi
    f32x16 sT = (f32x16)0.0f;
    __builtin_amdgcn_s_setprio(1);
#pragma unroll
    for (int kk = 0; kk < 4; kk++) sT = mfma32(kf[kk], qf[kk], sT);
    __builtin_amdgcn_s_setprio(0);

    // scale + mask-bias; tree row-max (2 lanes per row)
#pragma unroll
    for (int r = 0; r < 16; r++) sT[r] = fmaf(sT[r], SC, b4[r >> 2][r & 3]);
    float tm0 = fmaxf(fmaxf(sT[0], sT[1]), fmaxf(sT[2], sT[3]));
    float tm1 = fmaxf(fmaxf(sT[4], sT[5]), fmaxf(sT[6], sT[7]));
    float tm2 = fmaxf(fmaxf(sT[8], sT[9]), fmaxf(sT[10], sT[11]));
    float tm3 = fmaxf(fmaxf(sT[12], sT[13]), fmaxf(sT[14], sT[15]));
    float tm = fmaxf(fmaxf(tm0, tm1), fmaxf(tm2, tm3));
    tm = fmaxf(tm, __shfl_xor(tm, 32));

    // defer-max: rescale only when some row's max grew past threshold
    if (!__all(tm <= m_run + 8.0f)) {
      float mn = fmaxf(m_run, tm);
      float corr = exp2f(m_run - mn);
      m_run = mn;
      l_run *= corr;
      if (hi == 0) corrL[l31] = corr;  // wave-private; lgkmcnt orders
      float4 c4[4];
#pragma unroll
      for (int m = 0; m < 4; m++)
        c4[m] = *(const float4*)(corrL + m * 8 + hi * 4);
#pragma unroll
      for (int r = 0; r < 16; r++) {
        float cq = c4[r >> 2][r & 3];
        acc[0][r] *= cq;
        acc[1][r] *= cq;
      }
    }

    // P = exp2(S - m); tree row-sum
    float p[16];
#pragma unroll
    for (int r = 0; r < 16; r++) p[r] = exp2f(sT[r] - m_run);
    float rs0 = (p[0] + p[1]) + (p[2] + p[3]);
    float rs1 = (p[4] + p[5]) + (p[6] + p[7]);
    float rs2 = (p[8] + p[9]) + (p[10] + p[11]);
    float rs3 = (p[12] + p[13]) + (p[14] + p[15]);
    float rs = (rs0 + rs1) + (rs2 + rs3);
    rs += __shfl_xor(rs, 32);
    l_run += rs;

    // pack P -> bf16 pairs; redistribute halves with v_permlane32_swap:
    // after swap(c0,c2),(c1,c3): {c0,c1,c2,c3} is the ks=0 A-frag for BOTH
    // lane halves; swap(c4,c6),(c5,c7) likewise for ks=1.
    u32 c[8];
#pragma unroll
    for (int i = 0; i < 8; i++) c[i] = cvtpk(p[2 * i], p[2 * i + 1]);
    asm volatile("v_permlane32_swap_b32 %0, %1" : "+v"(c[0]), "+v"(c[2]));
    asm volatile("v_permlane32_swap_b32 %0, %1" : "+v"(c[1]), "+v"(c[3]));
    asm volatile("v_permlane32_swap_b32 %0, %1" : "+v"(c[4]), "+v"(c[6]));
    asm volatile("v_permlane32_swap_b32 %0, %1" : "+v"(c[5]), "+v"(c[7]));
    u32x4 w0, w1;
    w0.x = c[0]; w0.y = c[1]; w0.z = c[2]; w0.w = c[3];
    w1.x = c[4]; w1.y = c[5]; w1.z = c[6]; w1.w = c[7];
    bf16x8 pa0 = __builtin_bit_cast(bf16x8, w0);
    bf16x8 pa1 = __builtin_bit_cast(bf16x8, w1);

    // O += P V
    __builtin_amdgcn_s_setprio(1);
    acc[0] = mfma32(pa0, vf[0][0], acc[0]);
    acc[1] = mfma32(pa0, vf[1][0], acc[1]);
    acc[0] = mfma32(pa1, vf[0][1], acc[0]);
    acc[1] = mfma32(pa1, vf[1][1], acc[1]);
    __builtin_amdgcn_s_setprio(0);

    // rotate K prefetch
#pragma unroll
    for (int kk = 0; kk < 4; kk++) kf[kk] = kn[kk];
  }

  // Merge the 4 KV-chunk partials via LDS
  __syncthreads();  // corrL dead; alias smem as accL/mlL
  float* accL = (float*)smem;           // [kc][row 0..63][65] padded
  float* mlL = (float*)(smem + 66560);  // [kc][row][2]
#pragma unroll
  for (int ht = 0; ht < 2; ht++)
#pragma unroll
    for (int r = 0; r < 16; r++) {
      int q = (r & 3) + 8 * (r >> 2) + 4 * hi;
      accL[(kc * 64 + qt * 32 + q) * 65 + ht * 32 + l31] = acc[ht][r];
    }
  if (hi == 0) {
    mlL[(kc * 64 + qt * 32 + l31) * 2 + 0] = m_run;
    mlL[(kc * 64 + qt * 32 + l31) * 2 + 1] = l_run;
  }
  __syncthreads();

#pragma unroll
  for (int i = 0; i < 8; i++) {
    int idx = tid + i * 512;  // 0..4095
    int row = idx >> 6, h = idx & 63;
    float m[4], l[4];
#pragma unroll
    for (int z = 0; z < 4; z++) {
      m[z] = mlL[(z * 64 + row) * 2 + 0];
      l[z] = mlL[(z * 64 + row) * 2 + 1];
    }
    float M = fmaxf(fmaxf(m[0], m[1]), fmaxf(m[2], m[3]));
    float den = 0.0f, o = 0.0f;
#pragma unroll
    for (int z = 0; z < 4; z++) {
      float e = exp2f(m[z] - M);
      den += e * l[z];
      o += e * accL[(z * 64 + row) * 65 + h];
    }
    out[((size_t)b * NS + qp * 64 + row) * NH + h] = o / den;
  }
}

extern "C" void kernel_launch(void* const* d_in, const int* in_sizes, int n_in,
                              void* d_out, int out_size, void* d_ws,
                              size_t ws_size, hipStream_t stream) {
  const float* inp = (const float*)d_in[0];
  const int* mask = (const int*)d_in[1];
  const float* Wq = (const float*)d_in[2];
  const float* bq = (const float*)d_in[3];
  const float* Wk = (const float*)d_in[4];
  const float* bk = (const float*)d_in[5];
  const float* Wv = (const float*)d_in[6];
  const float* bv = (const float*)d_in[7];
  float* out = (float*)d_out;

  char* ws = (char*)d_ws;
  u16* wsW = (u16*)ws;                              // 288 KB
  u16* wsQf = (u16*)(ws + (1u << 20));              // 4 MB
  u16* wsKf = (u16*)(ws + (1u << 20) + (4u << 20)); // 4 MB
  u16* wsVf = (u16*)(ws + (1u << 20) + (8u << 20)); // 4 MB
  float* wsBias = (float*)(ws + (13u << 20));       // 128 KB

  prep_weights<<<dim3(72), dim3(256), 0, stream>>>(Wq, Wk, Wv, wsW);
  prep_bias<<<dim3(NB * NS / 256), dim3(256), 0, stream>>>(mask, wsBias);
  qkv_proj<<<dim3((NB * NS) / 32), dim3(256), 0, stream>>>(inp, wsW, bq, bk,
                                                           bv, wsQf, wsKf, wsVf);
  attn<<<dim3(NB * NS / 64), dim3(512), 0, stream>>>(wsQf, wsKf, wsVf, wsBias,
                                                     out);
}

// Round 7
// 78.056 us; speedup vs baseline: 1.3741x; 1.3741x over previous
//
#include <hip/hip_runtime.h>

typedef short bf16x8 __attribute__((ext_vector_type(8)));
typedef float f32x4 __attribute__((ext_vector_type(4)));
typedef float f32x16 __attribute__((ext_vector_type(16)));
typedef unsigned int u32x4 __attribute__((ext_vector_type(4)));
typedef unsigned short u16;
typedef unsigned int u32;

#define DEVI static __device__ __forceinline__

// Problem constants
#define NB 16
#define NS 2048
#define NW 768
#define NH 64

DEVI u16 f2bf(float x) {
  u32 u = __builtin_bit_cast(u32, x);
  u += 0x7fffu + ((u >> 16) & 1u);
  return (u16)(u >> 16);
}

DEVI u32 cvtpk(float lo, float hi) {
  u32 r;
  asm("v_cvt_pk_bf16_f32 %0, %1, %2" : "=v"(r) : "v"(lo), "v"(hi));
  return r;
}

DEVI f32x4 mfma16(bf16x8 a, bf16x8 b, f32x4 c) {
  return __builtin_amdgcn_mfma_f32_16x16x32_bf16(a, b, c, 0, 0, 0);
}
DEVI f32x16 mfma32(bf16x8 a, bf16x8 b, f32x16 c) {
  return __builtin_amdgcn_mfma_f32_32x32x16_bf16(a, b, c, 0, 0, 0);
}

// XOR swizzle for width-64-bf16 LDS tiles (128B row stride).
DEVI int swz(int row, int col) { return ((row * 64 + col) * 2) ^ ((row & 7) << 4); }

// ---------------------------------------------------------------------------
// Fragment-linear layouts (attention loads are base + lane*16B, coalesced):
//   Q_frag/K_frag: u16[(b*64+T)][kk=0..3][lane=hi*32+l31][j=0..7]
//     holds (s, n) with T=s>>5, l31=s&31, kk=n>>4, hi=(n>>3)&1, j=n&7.
//   V_frag: u16[(b*64+T)][ks=0..1][ht=0..1][lane=hi*32+(h&31)][j]
//     holds (s, h) with ks=bit4(s&31), hi=bit3(s&31), j=s&7, ht=h>>5.
// ---------------------------------------------------------------------------

// ---------------------------------------------------------------------------
// Kernel 0: rearrange Wq/Wk/Wv (fp32 [768][64]) into bf16 MFMA-B-fragment order.
// ---------------------------------------------------------------------------
__global__ __launch_bounds__(256) void prep_weights(
    const float* __restrict__ Wq, const float* __restrict__ Wk,
    const float* __restrict__ Wv, u16* __restrict__ wsW) {
  int tid = blockIdx.x * 256 + threadIdx.x;
  int tile = tid >> 6, lane = tid & 63;
  int p = tile / 96, rem = tile % 96;
  int nct = rem / 24, kch = rem % 24;
  const float* Wsrc = (p == 0) ? Wq : ((p == 1) ? Wk : Wv);
  int k0 = kch * 32 + (lane >> 4) * 8;
  int n = nct * 16 + (lane & 15);
  u16 h[8];
#pragma unroll
  for (int i = 0; i < 8; i++) h[i] = f2bf(Wsrc[(k0 + i) * NH + n]);
  uint4 v;
  v.x = (u32)h[0] | ((u32)h[1] << 16);
  v.y = (u32)h[2] | ((u32)h[3] << 16);
  v.z = (u32)h[4] | ((u32)h[5] << 16);
  v.w = (u32)h[6] | ((u32)h[7] << 16);
  ((uint4*)wsW)[tile * 64 + lane] = v;
}

// ---------------------------------------------------------------------------
// Kernel 1: fused QKV projection. BM=64, 512 threads, 8 waves (wr 0..1 rows,
// wc 0..3 col-groups of 48). Depth-2 A prefetch: loads for chunk t+1 issued
// at iter t-1 (regs), ds_write at iter t, compute at t+1. Double LDS buffer,
// ONE barrier per chunk. W fragments register-prefetched depth-1 (L2-hit).
// Outputs in fragment-linear order.
// ---------------------------------------------------------------------------
__global__ __launch_bounds__(512, 4) void qkv_proj(
    const float* __restrict__ inp, const u16* __restrict__ wsW,
    const float* __restrict__ bq, const float* __restrict__ bk,
    const float* __restrict__ bv, u16* __restrict__ Qf, u16* __restrict__ Kf,
    u16* __restrict__ Vf) {
  __shared__ __align__(16) u16 A_lds[2][64 * 64];  // 2 x 8 KB, swizzled
  int tid = threadIdx.x;
  int w = tid >> 6, lane = tid & 63, g = lane >> 4, l15 = lane & 15;
  int wr = w >> 2, wc = w & 3;
  int row0 = blockIdx.x * 64;
  int sr0 = tid >> 4, sc4 = (tid & 15) * 4, sr1 = sr0 + 32;
  const float* base = inp + (size_t)row0 * NW;

  f32x4 acc[2][3];
#pragma unroll
  for (int rt = 0; rt < 2; rt++)
#pragma unroll
    for (int ct = 0; ct < 3; ct++) acc[rt][ct] = (f32x4)0.0f;

  float4 a0, a1;
  bf16x8 wreg[3][2], wnxt[3][2];

  // Prologue: load chunk0 (A+W), stage chunk0 -> buf0, load chunk1 (A+W).
  a0 = *(const float4*)(base + (size_t)sr0 * NW + sc4);
  a1 = *(const float4*)(base + (size_t)sr1 * NW + sc4);
#pragma unroll
  for (int ct = 0; ct < 3; ct++)
#pragma unroll
    for (int kk = 0; kk < 2; kk++)
      wreg[ct][kk] = *(const bf16x8*)(
          wsW + (size_t)((wc * 3 + ct) * 24 + kk) * 512 + lane * 8);
  {
    ushort4 h4;
    h4.x = f2bf(a0.x); h4.y = f2bf(a0.y); h4.z = f2bf(a0.z); h4.w = f2bf(a0.w);
    *(ushort4*)((char*)A_lds[0] + swz(sr0, sc4)) = h4;
    h4.x = f2bf(a1.x); h4.y = f2bf(a1.y); h4.z = f2bf(a1.z); h4.w = f2bf(a1.w);
    *(ushort4*)((char*)A_lds[0] + swz(sr1, sc4)) = h4;
  }
  a0 = *(const float4*)(base + (size_t)sr0 * NW + 64 + sc4);
  a1 = *(const float4*)(base + (size_t)sr1 * NW + 64 + sc4);
#pragma unroll
  for (int ct = 0; ct < 3; ct++)
#pragma unroll
    for (int kk = 0; kk < 2; kk++)
      wnxt[ct][kk] = *(const bf16x8*)(
          wsW + (size_t)((wc * 3 + ct) * 24 + 2 + kk) * 512 + lane * 8);
  __syncthreads();

  int cur = 0;
  for (int t = 0; t < 12; t++) {
    if (t < 11) {
      // stage chunk t+1 (regs loaded at iter t-1) into the other buffer
      ushort4 h4;
      h4.x = f2bf(a0.x); h4.y = f2bf(a0.y); h4.z = f2bf(a0.z); h4.w = f2bf(a0.w);
      *(ushort4*)((char*)A_lds[cur ^ 1] + swz(sr0, sc4)) = h4;
      h4.x = f2bf(a1.x); h4.y = f2bf(a1.y); h4.z = f2bf(a1.z); h4.w = f2bf(a1.w);
      *(ushort4*)((char*)A_lds[cur ^ 1] + swz(sr1, sc4)) = h4;
      // issue loads for chunk t+2 (clamped; final redundant load unused)
      int c2 = (t < 10) ? t + 2 : 11;
      a0 = *(const float4*)(base + (size_t)sr0 * NW + c2 * 64 + sc4);
      a1 = *(const float4*)(base + (size_t)sr1 * NW + c2 * 64 + sc4);
    }
    // compute chunk t from buf[cur] with wreg
    bf16x8 af[2][2];
#pragma unroll
    for (int rt = 0; rt < 2; rt++)
#pragma unroll
      for (int kk = 0; kk < 2; kk++)
        af[rt][kk] = *(const bf16x8*)((const char*)A_lds[cur] +
                                      swz(wr * 32 + rt * 16 + l15,
                                          kk * 32 + g * 8));
#pragma unroll
    for (int ct = 0; ct < 3; ct++)
#pragma unroll
      for (int kk = 0; kk < 2; kk++) {
        acc[0][ct] = mfma16(af[0][kk], wreg[ct][kk], acc[0][ct]);
        acc[1][ct] = mfma16(af[1][kk], wreg[ct][kk], acc[1][ct]);
      }
    // rotate W prefetch
    if (t < 11) {
      int c2 = (t < 10) ? t + 2 : 11;
#pragma unroll
      for (int ct = 0; ct < 3; ct++)
#pragma unroll
        for (int kk = 0; kk < 2; kk++) {
          wreg[ct][kk] = wnxt[ct][kk];
          wnxt[ct][kk] = *(const bf16x8*)(
              wsW + (size_t)((wc * 3 + ct) * 24 + c2 * 2 + kk) * 512 + lane * 8);
        }
    }
    __syncthreads();
    cur ^= 1;
  }

  // Epilogue: bias add, store in fragment-linear order.
  int b = row0 >> 11;
  size_t bT = (size_t)b * 64 + ((row0 & 2047) >> 5) + wr;
#pragma unroll
  for (int ct = 0; ct < 3; ct++) {
    int gct = wc * 3 + ct;
    int p3 = gct >> 2;
    int n = (gct & 3) * 16 + l15;
    const float* bias = (p3 == 0) ? bq : ((p3 == 1) ? bk : bv);
    float bbv = bias[n];
    if (p3 < 2) {
      u16* basep = (p3 == 0) ? Qf : Kf;
      int kk = gct & 3;
      int hin = (l15 >> 3) & 1, j = l15 & 7;
#pragma unroll
      for (int rt = 0; rt < 2; rt++)
#pragma unroll
        for (int reg = 0; reg < 4; reg++)
          basep[((bT * 4 + kk) * 64 + hin * 32 + rt * 16 + g * 4 + reg) * 8 + j] =
              f2bf(acc[rt][ct][reg] + bbv);
    } else {
      int ht = n >> 5, lanev = ((g >> 1) & 1) * 32 + (n & 31), jb = (g & 1) * 4;
#pragma unroll
      for (int rt = 0; rt < 2; rt++) {
        uint2 pp;
        pp.x = (u32)f2bf(acc[rt][ct][0] + bbv) |
               ((u32)f2bf(acc[rt][ct][1] + bbv) << 16);
        pp.y = (u32)f2bf(acc[rt][ct][2] + bbv) |
               ((u32)f2bf(acc[rt][ct][3] + bbv) << 16);
        *(uint2*)(Vf + (((bT * 2 + rt) * 2 + ht) * 64 + lanev) * 8 + jb) = pp;
      }
    }
  }
}

// ---------------------------------------------------------------------------
// Kernel 2: flash attention, 32x32 MFMA, fragment-linear operands.
// Block: 64 q-rows x batch, 8 waves = 2 q-tiles x 4 KV-chunks (L1 dedups the
// shared K/V lines). Swapped QK^T; mask folded in as select; defer-max;
// P packed via cvt_pk + v_permlane32_swap; setprio around MFMA clusters.
// ---------------------------------------------------------------------------
__global__ __launch_bounds__(512) void attn(
    const u16* __restrict__ Qf, const u16* __restrict__ Kf,
    const u16* __restrict__ Vf, const int* __restrict__ mask,
    float* __restrict__ out) {
  // Main loop: corrL (8 waves x 32 f32, wave-private). After the final
  // barrier aliased as accL[4][64][65] f32 + mlL[4][64][2] f32.
  __shared__ __align__(16) char smem[68608];
  int tid = threadIdx.x;
  int w = tid >> 6, lane = tid & 63;
  int l31 = lane & 31, hi = lane >> 5;
  int qt = w >> 2, kc = w & 3;
  int bid = blockIdx.x;
  int b = (bid & 7) * 2 + ((bid >> 3) & 1);  // 2 batches per XCD (L2 locality)
  int qp = bid >> 4;                         // 64-q pair index 0..31
  const int* mb = mask + (size_t)b * NS;
  float* corrL = (float*)smem + w * 32;

  const float SC = 0.18033688011112043f;  // log2(e)/sqrt(64)

  // Q fragments for this wave's q-tile
  size_t bQT = (size_t)b * 64 + qp * 2 + qt;
  bf16x8 qf[4];
#pragma unroll
  for (int kk = 0; kk < 4; kk++)
    qf[kk] = *(const bf16x8*)(Qf + (bQT * 4 + kk) * 512 + lane * 8);

  f32x16 acc[2];
  acc[0] = (f32x16)0.0f;
  acc[1] = (f32x16)0.0f;
  float m_run = -1.0e4f, l_run = 0.0f;

  // First K tile of this wave's 512-key chunk
  size_t tbase = (size_t)b * 64 + kc * 16;
  bf16x8 kf[4];
#pragma unroll
  for (int kk = 0; kk < 4; kk++)
    kf[kk] = *(const bf16x8*)(Kf + (tbase * 4 + kk) * 512 + lane * 8);

  for (int t = 0; t < 16; t++) {
    int kv0 = kc * 512 + t * 32;
    size_t bKT = tbase + t;
    size_t bKN = tbase + ((t < 15) ? t + 1 : t);
    // Prefetch next K tile (register double-buffer)
    bf16x8 kn[4];
#pragma unroll
    for (int kk = 0; kk < 4; kk++)
      kn[kk] = *(const bf16x8*)(Kf + (bKN * 4 + kk) * 512 + lane * 8);
    // V fragments + mask: issued now, consumed after softmax (self-hiding)
    bf16x8 vf[2][2];
#pragma unroll
    for (int ht = 0; ht < 2; ht++)
#pragma unroll
      for (int ks = 0; ks < 2; ks++)
        vf[ht][ks] = *(const bf16x8*)(Vf + ((bKT * 2 + ks) * 2 + ht) * 512 +
                                      lane * 8);
    int mqa[16];
#pragma unroll
    for (int m = 0; m < 4; m++) {
      int4 v = *(const int4*)(mb + kv0 + m * 8 + hi * 4);
      mqa[m * 4 + 0] = v.x;
      mqa[m * 4 + 1] = v.y;
      mqa[m * 4 + 2] = v.z;
      mqa[m * 4 + 3] = v.w;
    }

    // S^T[key][q] : lane holds q=l31, keys (r&3)+8*(r>>2)+4*hi
    f32x16 sT = (f32x16)0.0f;
    __builtin_amdgcn_s_setprio(1);
#pragma unroll
    for (int kk = 0; kk < 4; kk++) sT = mfma32(kf[kk], qf[kk], sT);
    __builtin_amdgcn_s_setprio(0);

    // scale + mask (select); tree row-max (2 lanes per row)
#pragma unroll
    for (int r = 0; r < 16; r++) sT[r] = mqa[r] ? sT[r] * SC : -1.0e5f;
    float tm0 = fmaxf(fmaxf(sT[0], sT[1]), fmaxf(sT[2], sT[3]));
    float tm1 = fmaxf(fmaxf(sT[4], sT[5]), fmaxf(sT[6], sT[7]));
    float tm2 = fmaxf(fmaxf(sT[8], sT[9]), fmaxf(sT[10], sT[11]));
    float tm3 = fmaxf(fmaxf(sT[12], sT[13]), fmaxf(sT[14], sT[15]));
    float tm = fmaxf(fmaxf(tm0, tm1), fmaxf(tm2, tm3));
    tm = fmaxf(tm, __shfl_xor(tm, 32));

    // defer-max: rescale only when some row's max grew past threshold
    if (!__all(tm <= m_run + 8.0f)) {
      float mn = fmaxf(m_run, tm);
      float corr = exp2f(m_run - mn);
      m_run = mn;
      l_run *= corr;
      if (hi == 0) corrL[l31] = corr;  // wave-private; lgkmcnt orders
      float4 c4[4];
#pragma unroll
      for (int m = 0; m < 4; m++)
        c4[m] = *(const float4*)(corrL + m * 8 + hi * 4);
#pragma unroll
      for (int r = 0; r < 16; r++) {
        float cq = c4[r >> 2][r & 3];
        acc[0][r] *= cq;
        acc[1][r] *= cq;
      }
    }

    // P = exp2(S - m); tree row-sum
    float p[16];
#pragma unroll
    for (int r = 0; r < 16; r++) p[r] = exp2f(sT[r] - m_run);
    float rs0 = (p[0] + p[1]) + (p[2] + p[3]);
    float rs1 = (p[4] + p[5]) + (p[6] + p[7]);
    float rs2 = (p[8] + p[9]) + (p[10] + p[11]);
    float rs3 = (p[12] + p[13]) + (p[14] + p[15]);
    float rs = (rs0 + rs1) + (rs2 + rs3);
    rs += __shfl_xor(rs, 32);
    l_run += rs;

    // pack P -> bf16 pairs; redistribute halves with v_permlane32_swap
    u32 c[8];
#pragma unroll
    for (int i = 0; i < 8; i++) c[i] = cvtpk(p[2 * i], p[2 * i + 1]);
    asm volatile("v_permlane32_swap_b32 %0, %1" : "+v"(c[0]), "+v"(c[2]));
    asm volatile("v_permlane32_swap_b32 %0, %1" : "+v"(c[1]), "+v"(c[3]));
    asm volatile("v_permlane32_swap_b32 %0, %1" : "+v"(c[4]), "+v"(c[6]));
    asm volatile("v_permlane32_swap_b32 %0, %1" : "+v"(c[5]), "+v"(c[7]));
    u32x4 w0, w1;
    w0.x = c[0]; w0.y = c[1]; w0.z = c[2]; w0.w = c[3];
    w1.x = c[4]; w1.y = c[5]; w1.z = c[6]; w1.w = c[7];
    bf16x8 pa0 = __builtin_bit_cast(bf16x8, w0);
    bf16x8 pa1 = __builtin_bit_cast(bf16x8, w1);

    // O += P V
    __builtin_amdgcn_s_setprio(1);
    acc[0] = mfma32(pa0, vf[0][0], acc[0]);
    acc[1] = mfma32(pa0, vf[1][0], acc[1]);
    acc[0] = mfma32(pa1, vf[0][1], acc[0]);
    acc[1] = mfma32(pa1, vf[1][1], acc[1]);
    __builtin_amdgcn_s_setprio(0);

    // rotate K prefetch
#pragma unroll
    for (int kk = 0; kk < 4; kk++) kf[kk] = kn[kk];
  }

  // Merge the 4 KV-chunk partials via LDS
  __syncthreads();  // corrL dead; alias smem as accL/mlL
  float* accL = (float*)smem;           // [kc][row 0..63][65] padded
  float* mlL = (float*)(smem + 66560);  // [kc][row][2]
#pragma unroll
  for (int ht = 0; ht < 2; ht++)
#pragma unroll
    for (int r = 0; r < 16; r++) {
      int q = (r & 3) + 8 * (r >> 2) + 4 * hi;
      accL[(kc * 64 + qt * 32 + q) * 65 + ht * 32 + l31] = acc[ht][r];
    }
  if (hi == 0) {
    mlL[(kc * 64 + qt * 32 + l31) * 2 + 0] = m_run;
    mlL[(kc * 64 + qt * 32 + l31) * 2 + 1] = l_run;
  }
  __syncthreads();

#pragma unroll
  for (int i = 0; i < 8; i++) {
    int idx = tid + i * 512;  // 0..4095
    int row = idx >> 6, h = idx & 63;
    float m[4], l[4];
#pragma unroll
    for (int z = 0; z < 4; z++) {
      m[z] = mlL[(z * 64 + row) * 2 + 0];
      l[z] = mlL[(z * 64 + row) * 2 + 1];
    }
    float M = fmaxf(fmaxf(m[0], m[1]), fmaxf(m[2], m[3]));
    float den = 0.0f, o = 0.0f;
#pragma unroll
    for (int z = 0; z < 4; z++) {
      float e = exp2f(m[z] - M);
      den += e * l[z];
      o += e * accL[(z * 64 + row) * 65 + h];
    }
    out[((size_t)b * NS + qp * 64 + row) * NH + h] = o / den;
  }
}

extern "C" void kernel_launch(void* const* d_in, const int* in_sizes, int n_in,
                              void* d_out, int out_size, void* d_ws,
                              size_t ws_size, hipStream_t stream) {
  const float* inp = (const float*)d_in[0];
  const int* mask = (const int*)d_in[1];
  const float* Wq = (const float*)d_in[2];
  const float* bq = (const float*)d_in[3];
  const float* Wk = (const float*)d_in[4];
  const float* bk = (const float*)d_in[5];
  const float* Wv = (const float*)d_in[6];
  const float* bv = (const float*)d_in[7];
  float* out = (float*)d_out;

  char* ws = (char*)d_ws;
  u16* wsW = (u16*)ws;                              // 288 KB
  u16* wsQf = (u16*)(ws + (1u << 20));              // 4 MB
  u16* wsKf = (u16*)(ws + (1u << 20) + (4u << 20)); // 4 MB
  u16* wsVf = (u16*)(ws + (1u << 20) + (8u << 20)); // 4 MB

  prep_weights<<<dim3(72), dim3(256), 0, stream>>>(Wq, Wk, Wv, wsW);
  qkv_proj<<<dim3((NB * NS) / 64), dim3(512), 0, stream>>>(inp, wsW, bq, bk,
                                                           bv, wsQf, wsKf, wsVf);
  attn<<<dim3(NB * NS / 64), dim3(512), 0, stream>>>(wsQf, wsKf, wsVf, mask,
                                                     out);
}